// Round 2
// baseline (419.296 us; speedup 1.0000x reference)
//
#include <hip/hip_runtime.h>

// YOLO-style loss: pred/target (bs, 7, 7, 30) fp32 -> scalar.
// S=7, B=2 boxes (5 ch each), C=20 classes. Memory-bound streaming reduction.
//
// v3: split the math by access pattern.
//  - Class loss (ch 10..29) and noobj-conf loss (ch 4, 9) are elementwise in
//    (p - t): computed in a FULLY COALESCED float2 sweep (thread k handles
//    pairs tid + 256k of the block's 7680-float range), with the per-cell
//    obj weight deferred through a 1 KB LDS obj-flag table.
//  - Only box/IoU (ch 0..9) needs per-cell gathering: 10 divergent float2
//    loads per thread (was 30 in v2). v2's wall was L1 transaction rate:
//    each divergent wave-load spans 64 lanes x 120 B = ~61 cache lines, so
//    30+30 loads/wave = ~3660 line-txns (~150 us of TCP work at 1 line/cy).
//    v3 cuts that to ~730/wave (~30 us), below the ~60 us HBM floor.
// Reduction tree unchanged. Pass 2: single block reduces partials -> out[0].
// Fallback (ws too small): zero-init + one atomicAdd per block.

#define CH 30
#define SDIV 7.0f

__device__ __forceinline__ float2 ld2(const float* __restrict__ p, long long off) {
    return *reinterpret_cast<const float2*>(p + off);
}

template <bool USE_ATOMIC>
__global__ __launch_bounds__(256) void yolo_loss_pass1(
    const float* __restrict__ pred, const float* __restrict__ tgt,
    float* __restrict__ dst, long long n_cells, float scale)
{
    __shared__ float lds_obj[256];
    __shared__ float wsums[4];

    const int tid = threadIdx.x;
    const long long cell0 = (long long)blockIdx.x * 256;
    const long long cell  = cell0 + tid;
    const bool live = (cell < n_cells);

    float acc = 0.0f;

    // ---------- coalesced sweep: per-pair squared diffs, weights deferred ----
    // Block's element range is [cell0*30, cell0*30 + 7680): 3840 float2 pairs,
    // 15 per thread at pair-stride 256. e = 2*(tid + 256k); ch = e%30; cl = e/30.
    // Pair never straddles a cell: e is even and 30 is even, so ch <= 28.
    const float* __restrict__ pblk = pred + cell0 * CH;
    const float* __restrict__ tblk = tgt  + cell0 * CH;
    const long long rem_f = (n_cells - cell0) * CH;   // valid floats in range

    float s[15];
    {
        int ch = (2 * tid) % 30;                      // channel of pair .x
        #pragma unroll
        for (int k = 0; k < 15; ++k) {
            const int e = 2 * (tid + 256 * k);
            float sv = 0.0f;
            if ((long long)e < rem_f) {
                const float2 pv = ld2(pblk, e);
                const float2 tv = ld2(tblk, e);
                const float dx = pv.x - tv.x;
                const float dy = pv.y - tv.y;
                if (ch >= 10)      sv = dx * dx + dy * dy;  // both class
                else if (ch == 4)  sv = dx * dx;            // conf ch4 (.y is ch5: box)
                else if (ch == 8)  sv = dy * dy;            // conf ch9 (.x is ch8: box)
                // ch 0,2,6: pure box channels -> handled in gather phase
            }
            s[k] = sv;
            ch += 2; if (ch >= 30) ch -= 30;          // e step 512 == 2 (mod 30)
        }
    }

    // ---------- per-cell box / IoU: 10 divergent float2 loads ----------
    if (live) {
        const float* __restrict__ p = pred + cell * CH;
        const float* __restrict__ t = tgt  + cell * CH;

        const float2 pa = ld2(p, 0), pb = ld2(p, 2), pc = ld2(p, 4),
                     pd = ld2(p, 6), pe = ld2(p, 8);
        const float2 ta = ld2(t, 0), tb = ld2(t, 2), tc = ld2(t, 4),
                     td = ld2(t, 6), te = ld2(t, 8);

        const float obj = (tc.x > 0.0f) ? 1.0f : 0.0f;   // t[4]
        lds_obj[tid] = obj;

        // target box 0 -> xyxy (matches reference op order)
        const float t_x0 = ta.x / SDIV - 0.5f * tb.x;
        const float t_y0 = ta.y / SDIV - 0.5f * tb.y;
        const float t_x1 = ta.x / SDIV + 0.5f * tb.x;
        const float t_y1 = ta.y / SDIV + 0.5f * tb.y;
        const float area_t = (t_x1 - t_x0) * (t_y1 - t_y0);

        // pred box 0: ch 0..4 = pa.x pa.y pb.x pb.y pc.x
        float iou0;
        {
            const float x0 = pa.x / SDIV - 0.5f * pb.x;
            const float y0 = pa.y / SDIV - 0.5f * pb.y;
            const float x1 = pa.x / SDIV + 0.5f * pb.x;
            const float y1 = pa.y / SDIV + 0.5f * pb.y;
            const float ltx = fmaxf(x0, t_x0);
            const float lty = fmaxf(y0, t_y0);
            const float rbx = fminf(x1, t_x1);
            const float rby = fminf(y1, t_y1);
            const float w = fmaxf(rbx - ltx, 0.0f);
            const float h = fmaxf(rby - lty, 0.0f);
            const float inter  = w * h;
            const float area_p = (x1 - x0) * (y1 - y0);
            const float uni = fmaxf(area_p + area_t - inter, 1e-10f);
            iou0 = inter / uni;
        }
        // pred box 1: ch 5..9 = pc.y pd.x pd.y pe.x pe.y
        float iou1;
        {
            const float x0 = pc.y / SDIV - 0.5f * pd.y;
            const float y0 = pd.x / SDIV - 0.5f * pe.x;
            const float x1 = pc.y / SDIV + 0.5f * pd.y;
            const float y1 = pd.x / SDIV + 0.5f * pe.x;
            const float ltx = fmaxf(x0, t_x0);
            const float lty = fmaxf(y0, t_y0);
            const float rbx = fminf(x1, t_x1);
            const float rby = fminf(y1, t_y1);
            const float w = fmaxf(rbx - ltx, 0.0f);
            const float h = fmaxf(rby - lty, 0.0f);
            const float inter  = w * h;
            const float area_p = (x1 - x0) * (y1 - y0);
            const float uni = fmaxf(area_p + area_t - inter, 1e-10f);
            iou1 = inter / uni;
        }

        // jnp.argmax picks first on ties -> box1 only if strictly greater
        const bool  bsel    = (iou1 > iou0);
        const float max_iou = bsel ? iou1 : iou0;

        const float prx = bsel ? pc.y : pa.x;
        const float pry = bsel ? pd.x : pa.y;
        const float prw = bsel ? pd.y : pb.x;
        const float prh = bsel ? pe.x : pb.y;
        const float prc = bsel ? pe.y : pc.x;
        const float trx = bsel ? tc.y : ta.x;
        const float try_ = bsel ? td.x : ta.y;
        const float trw = bsel ? td.y : tb.x;
        const float trh = bsel ? te.x : tb.y;

        const float dx = prx - trx;
        const float dy = pry - try_;
        const float l_xy = dx * dx + dy * dy;
        const float dw = sqrtf(prw) - sqrtf(trw);
        const float dh = sqrtf(prh) - sqrtf(trh);
        const float l_wh = dw * dw + dh * dh;
        const float dc = prc - max_iou;
        const float l_obj = dc * dc;

        acc = obj * (5.0f * (l_xy + l_wh) + l_obj);
    } else {
        lds_obj[tid] = 0.0f;
    }
    __syncthreads();

    // ---------- weight sweep partials by per-cell obj flags ----------
    {
        int ch = (2 * tid) % 30;
        int cl = (2 * tid) / 30;
        #pragma unroll
        for (int k = 0; k < 15; ++k) {
            const float objf = lds_obj[cl];       // broadcast-heavy, ~free
            float w = 0.0f;
            if (ch >= 10)                w = objf;
            else if (ch == 4 || ch == 8) w = 0.5f * (1.0f - objf);
            acc += w * s[k];
            ch += 2; cl += 17;                    // e step 512 = 17*30 + 2
            if (ch >= 30) { ch -= 30; ++cl; }
        }
    }

    // ---- reduce: wave64 shuffle -> per-wave LDS -> per-block result ----
    float v = acc;
    #pragma unroll
    for (int off = 32; off > 0; off >>= 1)
        v += __shfl_down(v, off, 64);

    const int wave = tid >> 6;
    const int lane = tid & 63;
    if (lane == 0) wsums[wave] = v;
    __syncthreads();
    if (tid == 0) {
        const float sum = wsums[0] + wsums[1] + wsums[2] + wsums[3];
        if (USE_ATOMIC) atomicAdd(dst, sum * scale);
        else            dst[blockIdx.x] = sum;
    }
}

__global__ __launch_bounds__(256) void yolo_loss_pass2(
    const float* __restrict__ partials, float* __restrict__ out,
    int n_partials, float scale)
{
    __shared__ float wsums[4];
    const int tid = threadIdx.x;

    float v = 0.0f;
    for (int i = tid; i < n_partials; i += 256)
        v += partials[i];

    #pragma unroll
    for (int off = 32; off > 0; off >>= 1)
        v += __shfl_down(v, off, 64);

    const int wave = tid >> 6;
    const int lane = tid & 63;
    if (lane == 0) wsums[wave] = v;
    __syncthreads();
    if (tid == 0)
        out[0] = (wsums[0] + wsums[1] + wsums[2] + wsums[3]) * scale;
}

__global__ __launch_bounds__(64) void zero_out_kernel(float* out) {
    if (threadIdx.x == 0) out[0] = 0.0f;
}

extern "C" void kernel_launch(void* const* d_in, const int* in_sizes, int n_in,
                              void* d_out, int out_size, void* d_ws, size_t ws_size,
                              hipStream_t stream) {
    const float* pred = (const float*)d_in[0];
    const float* tgt  = (const float*)d_in[1];
    float* out = (float*)d_out;
    float* partials = (float*)d_ws;

    const long long total   = (long long)in_sizes[0];
    const long long n_cells = total / CH;          // bs*S*S
    const long long bs      = n_cells / 49;        // S*S = 49
    const float scale = 1.0f / (float)bs;

    const int grid = (int)((n_cells + 255) / 256);

    if (ws_size >= (size_t)grid * sizeof(float)) {
        // deterministic two-pass path
        yolo_loss_pass1<false><<<grid, 256, 0, stream>>>(pred, tgt, partials,
                                                         n_cells, scale);
        yolo_loss_pass2<<<1, 256, 0, stream>>>(partials, out, grid, scale);
    } else {
        // fallback: zero-init + one atomic per block
        zero_out_kernel<<<1, 64, 0, stream>>>(out);
        yolo_loss_pass1<true><<<grid, 256, 0, stream>>>(pred, tgt, out,
                                                        n_cells, scale);
    }
}